// Round 2
// baseline (4774.206 us; speedup 1.0000x reference)
//
#include <hip/hip_runtime.h>
#include <hip/hip_bf16.h>
#include <stdint.h>

#define DIM 128
#define BSTRIDE 136  // padded row stride (bf16 elems) for WkT in LDS

typedef float v4f __attribute__((ext_vector_type(4)));
typedef short v8s __attribute__((ext_vector_type(8)));

__device__ __forceinline__ unsigned short f2bf(float f) {
    union { float f; unsigned u; } c; c.f = f;
    unsigned r = c.u + 0x7fffu + ((c.u >> 16) & 1u);
    return (unsigned short)(r >> 16);
}

// pack two f32 -> bf16x2 (RNE), low half = lo
__device__ __forceinline__ unsigned pk_bf2(float lo, float hi) {
    __hip_bfloat162 h = __float22bfloat162_rn(make_float2(lo, hi));
    union { __hip_bfloat162 h; unsigned u; } c; c.h = h; return c.u;
}

__device__ __forceinline__ float bf2f(short s) {
    union { unsigned u; float f; } c; c.u = ((unsigned)(unsigned short)s) << 16;
    return c.f;
}

// ---------------- K0a: qry[b][d] = feat_u[b] @ W_user[:,d] + b_user[d] ----------------
__global__ void qry_kernel(const float* __restrict__ feat_u,
                           const float* __restrict__ W_user,
                           const float* __restrict__ b_user,
                           float* __restrict__ qry) {
    __shared__ float fu[DIM];
    int b = blockIdx.x, t = threadIdx.x;
    fu[t] = feat_u[b * DIM + t];
    __syncthreads();
    float acc = b_user[t];
#pragma unroll 8
    for (int k = 0; k < DIM; ++k) acc += fu[k] * W_user[k * DIM + t];
    qry[b * DIM + t] = acc;
}

// ---------------- K0b: WkT[d][k] (bf16, stride 136) = W_key[k][d] ----------------
__global__ void wkt_kernel(const float* __restrict__ W_key,
                           unsigned short* __restrict__ WkT) {
    int tid = blockIdx.x * blockDim.x + threadIdx.x;  // 16384 threads
    int k = tid >> 7, d = tid & 127;
    WkT[d * BSTRIDE + k] = f2bf(W_key[k * DIM + d]);
}

// ---------------- fused: GEMM -> e -> ex -> atomic {denom, Sum ex*feat_i} ----------------
// block = 256 threads (4 waves). Each wave: 8 strips of 16 nodes; block covers 512 nodes.
__global__ __launch_bounds__(256) void e_fused_kernel(const float* __restrict__ feat_i,
                                                      const int* __restrict__ seg,
                                                      const unsigned short* __restrict__ WkT,
                                                      const float* __restrict__ qry,
                                                      const float* __restrict__ W_e,
                                                      float* __restrict__ Wacc,
                                                      float* __restrict__ denom,
                                                      int N) {
    __shared__ __align__(16) unsigned short Blds[DIM * BSTRIDE];  // 34816 B
    __shared__ float We[DIM];
    const int t = threadIdx.x;

    {   // stage WkT -> LDS (16B chunks)
        const float4* src = (const float4*)WkT;
        float4* dst = (float4*)Blds;
        for (int i = t; i < (DIM * BSTRIDE) / 8; i += 256) dst[i] = src[i];
    }
    if (t < DIM) We[t] = W_e[t];
    __syncthreads();

    const int wave = t >> 6, lane = t & 63;
    const int m = lane & 15, quad = lane >> 4;
    const int base = blockIdx.x * 512 + wave * 128;

    // column accumulator: facc[kc*8+j] = sum over this lane's nodes of ex * feat_i[., d=kc*32+quad*8+j]
    float facc[32];
#pragma unroll
    for (int i = 0; i < 32; ++i) facc[i] = 0.f;
    int cur_sg = seg[min(base + m, N - 1)];

    // prefetch strip 0's A tile
    float4 pf[8];
    {
        const int n0 = base + m;
        const bool va = (n0 < N);
        const float* arow = feat_i + (size_t)(va ? n0 : 0) * DIM + quad * 8;
#pragma unroll
        for (int kc = 0; kc < 4; ++kc) {
            pf[2 * kc]     = va ? *(const float4*)(arow + kc * 32)     : make_float4(0.f, 0.f, 0.f, 0.f);
            pf[2 * kc + 1] = va ? *(const float4*)(arow + kc * 32 + 4) : make_float4(0.f, 0.f, 0.f, 0.f);
        }
    }

    for (int s = 0; s < 8; ++s) {
        const int strip = base + s * 16;

        // ---- convert prefetched A to bf16 fragments: A[m][k=kc*32+quad*8+j] ----
        v8s a[4];
#pragma unroll
        for (int kc = 0; kc < 4; ++kc) {
            union { v8s s8; unsigned u[4]; } av;
            av.u[0] = pk_bf2(pf[2 * kc].x,     pf[2 * kc].y);
            av.u[1] = pk_bf2(pf[2 * kc].z,     pf[2 * kc].w);
            av.u[2] = pk_bf2(pf[2 * kc + 1].x, pf[2 * kc + 1].y);
            av.u[3] = pk_bf2(pf[2 * kc + 1].z, pf[2 * kc + 1].w);
            a[kc] = av.s8;
        }

        // ---- prefetch next strip's A tile (overlaps MFMA + epilogue) ----
        if (s < 7) {
            const int n1 = strip + 16 + m;
            const bool va = (n1 < N);
            const float* arow = feat_i + (size_t)(va ? n1 : 0) * DIM + quad * 8;
#pragma unroll
            for (int kc = 0; kc < 4; ++kc) {
                pf[2 * kc]     = va ? *(const float4*)(arow + kc * 32)     : make_float4(0.f, 0.f, 0.f, 0.f);
                pf[2 * kc + 1] = va ? *(const float4*)(arow + kc * 32 + 4) : make_float4(0.f, 0.f, 0.f, 0.f);
            }
        }

        // ---- MFMA: 8 col-tiles x 4 K-chunks ----
        v4f acc[8];
#pragma unroll
        for (int c = 0; c < 8; ++c) acc[c] = (v4f){0.f, 0.f, 0.f, 0.f};
#pragma unroll
        for (int c = 0; c < 8; ++c) {
            const unsigned short* brow = Blds + (c * 16 + m) * BSTRIDE + quad * 8;
#pragma unroll
            for (int kc = 0; kc < 4; ++kc) {
                v8s b = *(const v8s*)(brow + kc * 32);
                acc[c] = __builtin_amdgcn_mfma_f32_16x16x32_bf16(a[kc], b, acc[c], 0, 0, 0);
            }
        }

        // ---- epilogue: C row = quad*4 + r, col = c*16 + m ----
        float exq[4];
#pragma unroll
        for (int r = 0; r < 4; ++r) {
            const int node = strip + quad * 4 + r;
            const bool nv = (node < N);
            const int sg = nv ? seg[node] : 0;
            const float* qrow = qry + sg * DIM;
            float partial = 0.f;
#pragma unroll
            for (int c = 0; c < 8; ++c) {
                const int d = c * 16 + m;
                const float x = acc[c][r] + qrow[d];
                const float sig = __builtin_amdgcn_rcpf(1.0f + __expf(-x));
                partial += sig * We[d];
            }
            partial += __shfl_xor(partial, 1);
            partial += __shfl_xor(partial, 2);
            partial += __shfl_xor(partial, 4);
            partial += __shfl_xor(partial, 8);
            const float ex = __expf(partial);
            exq[r] = ex;
            if (m == 0 && nv) atomicAdd(denom + sg, ex);
        }

        // ---- broadcast w = ex[strip+m] to the A-fragment owners of column m ----
        // node strip+m lives at quad'=m>>2, r'=m&3; any lane in that quad group has it.
        float w = 0.f;
#pragma unroll
        for (int r = 0; r < 4; ++r) {
            const float tv = __shfl(exq[r], (m >> 2) << 4);
            if ((m & 3) == r) w = tv;
        }
        const int n_a = strip + m;
        if (n_a >= N) w = 0.f;

        // ---- segment-boundary flush, then accumulate w * feat_i (bf16-rounded) ----
        const int sg_col = seg[min(n_a, N - 1)];
        if (sg_col != cur_sg) {
            float* dst = Wacc + (size_t)cur_sg * DIM + quad * 8;
#pragma unroll
            for (int kc = 0; kc < 4; ++kc)
#pragma unroll
                for (int j = 0; j < 8; ++j) {
                    atomicAdd(dst + kc * 32 + j, facc[kc * 8 + j]);
                    facc[kc * 8 + j] = 0.f;
                }
            cur_sg = sg_col;
        }
#pragma unroll
        for (int kc = 0; kc < 4; ++kc)
#pragma unroll
            for (int j = 0; j < 8; ++j)
                facc[kc * 8 + j] += w * bf2f(a[kc][j]);
    }

    // final flush
    {
        float* dst = Wacc + (size_t)cur_sg * DIM + quad * 8;
#pragma unroll
        for (int kc = 0; kc < 4; ++kc)
#pragma unroll
            for (int j = 0; j < 8; ++j)
                atomicAdd(dst + kc * 32 + j, facc[kc * 8 + j]);
    }
}

// ---------------- finalize: out[b][d] = Wacc[b][d] / denom[b] ----------------
__global__ void finalize_kernel(const float* __restrict__ Wacc,
                                const float* __restrict__ denom,
                                float* __restrict__ out) {
    const int b = blockIdx.x, t = threadIdx.x;
    const float d = denom[b];
    const float inv = (d > 0.f) ? 1.0f / d : 0.f;
    out[b * DIM + t] = Wacc[b * DIM + t] * inv;
}

extern "C" void kernel_launch(void* const* d_in, const int* in_sizes, int n_in,
                              void* d_out, int out_size, void* d_ws, size_t ws_size,
                              hipStream_t stream) {
    const float* feat_i = (const float*)d_in[0];
    const float* feat_u = (const float*)d_in[1];
    const int*   seg    = (const int*)d_in[2];
    const float* W_key  = (const float*)d_in[3];
    const float* W_user = (const float*)d_in[4];
    const float* b_user = (const float*)d_in[5];
    const float* W_e    = (const float*)d_in[6];
    float* out = (float*)d_out;

    const int N = in_sizes[2];
    const int B = in_sizes[1] / DIM;

    // workspace layout
    char* ws = (char*)d_ws;
    float*          qry   = (float*)ws;                          // 131072 B
    unsigned short* WkT   = (unsigned short*)(ws + 131072);      // 34816 B
    float*          denom = (float*)(ws + 131072 + 34816);       // B*4 (pad to 4096)
    float*          Wacc  = (float*)(ws + 131072 + 34816 + 4096);// B*DIM*4 = 131072 B

    hipMemsetAsync(denom, 0, (size_t)B * sizeof(float), stream);
    hipMemsetAsync(Wacc, 0, (size_t)B * DIM * sizeof(float), stream);

    qry_kernel<<<B, DIM, 0, stream>>>(feat_u, W_user, b_user, qry);
    wkt_kernel<<<(DIM * DIM) / 256, 256, 0, stream>>>(W_key, WkT);

    const int nblk = (N + 511) / 512;
    e_fused_kernel<<<nblk, 256, 0, stream>>>(feat_i, seg, WkT, qry, W_e, Wacc, denom, N);

    finalize_kernel<<<B, DIM, 0, stream>>>(Wacc, denom, out);
}

// Round 3
// 991.906 us; speedup vs baseline: 4.8132x; 4.8132x over previous
//
#include <hip/hip_runtime.h>
#include <hip/hip_bf16.h>
#include <stdint.h>

#define DIM 128
#define BSTRIDE 136  // padded row stride (bf16 elems) for WkT in LDS
#define NSLOT 16     // per-block segment accumulator slots (block spans ~2 segments typ.)

typedef float v4f __attribute__((ext_vector_type(4)));
typedef short v8s __attribute__((ext_vector_type(8)));

__device__ __forceinline__ unsigned short f2bf(float f) {
    union { float f; unsigned u; } c; c.f = f;
    unsigned r = c.u + 0x7fffu + ((c.u >> 16) & 1u);
    return (unsigned short)(r >> 16);
}

__device__ __forceinline__ unsigned pk_bf2(float lo, float hi) {
    __hip_bfloat162 h = __float22bfloat162_rn(make_float2(lo, hi));
    union { __hip_bfloat162 h; unsigned u; } c; c.h = h; return c.u;
}

__device__ __forceinline__ float bf2f(short s) {
    union { unsigned u; float f; } c; c.u = ((unsigned)(unsigned short)s) << 16;
    return c.f;
}

// ---------------- K0a: qry[b][d] = feat_u[b] @ W_user[:,d] + b_user[d] ----------------
__global__ void qry_kernel(const float* __restrict__ feat_u,
                           const float* __restrict__ W_user,
                           const float* __restrict__ b_user,
                           float* __restrict__ qry) {
    __shared__ float fu[DIM];
    int b = blockIdx.x, t = threadIdx.x;
    fu[t] = feat_u[b * DIM + t];
    __syncthreads();
    float acc = b_user[t];
#pragma unroll 8
    for (int k = 0; k < DIM; ++k) acc += fu[k] * W_user[k * DIM + t];
    qry[b * DIM + t] = acc;
}

// ---------------- K0b: WkT[d][k] (bf16, stride 136) = W_key[k][d] ----------------
__global__ void wkt_kernel(const float* __restrict__ W_key,
                           unsigned short* __restrict__ WkT) {
    int tid = blockIdx.x * blockDim.x + threadIdx.x;  // 16384 threads
    int k = tid >> 7, d = tid & 127;
    WkT[d * BSTRIDE + k] = f2bf(W_key[k * DIM + d]);
}

// ---------------- fused: GEMM -> e -> ex -> LDS segment accum -> one flush/block ----------------
// block = 256 threads (4 waves). Each wave: 8 strips of 16 nodes; block covers 512 nodes.
__global__ __launch_bounds__(256) void e_fused_kernel(const float* __restrict__ feat_i,
                                                      const int* __restrict__ seg,
                                                      const unsigned short* __restrict__ WkT,
                                                      const float* __restrict__ qry,
                                                      const float* __restrict__ W_e,
                                                      float* __restrict__ Wacc,
                                                      float* __restrict__ denom,
                                                      int N) {
    __shared__ __align__(16) unsigned short Blds[DIM * BSTRIDE];  // 34816 B
    __shared__ float We[DIM];
    __shared__ float slds[NSLOT * DIM];   // 8192 B  per-segment-slot column sums
    __shared__ float dlds[NSLOT];         // per-segment-slot denom sums
    const int t = threadIdx.x;

    {   // stage WkT -> LDS (16B chunks)
        const float4* src = (const float4*)WkT;
        float4* dst = (float4*)Blds;
        for (int i = t; i < (DIM * BSTRIDE) / 8; i += 256) dst[i] = src[i];
    }
    if (t < DIM) We[t] = W_e[t];
    for (int i = t; i < NSLOT * DIM; i += 256) slds[i] = 0.f;
    if (t < NSLOT) dlds[t] = 0.f;
    __syncthreads();

    const int wave = t >> 6, lane = t & 63;
    const int m = lane & 15, quad = lane >> 4;
    const int base_block = blockIdx.x * 512;
    const int base = base_block + wave * 128;
    const int sg_first = seg[min(base_block, N - 1)];

    // column accumulator: facc[kc*8+j] = sum over this lane's nodes of ex * feat_i[., d=kc*32+quad*8+j]
    float facc[32];
#pragma unroll
    for (int i = 0; i < 32; ++i) facc[i] = 0.f;
    int cur_sg = seg[min(base + m, N - 1)];

    // prefetch strip 0's A tile
    float4 pf[8];
    {
        const int n0 = base + m;
        const bool va = (n0 < N);
        const float* arow = feat_i + (size_t)(va ? n0 : 0) * DIM + quad * 8;
#pragma unroll
        for (int kc = 0; kc < 4; ++kc) {
            pf[2 * kc]     = va ? *(const float4*)(arow + kc * 32)     : make_float4(0.f, 0.f, 0.f, 0.f);
            pf[2 * kc + 1] = va ? *(const float4*)(arow + kc * 32 + 4) : make_float4(0.f, 0.f, 0.f, 0.f);
        }
    }

    for (int s = 0; s < 8; ++s) {
        const int strip = base + s * 16;

        // ---- convert prefetched A to bf16 fragments: A[m][k=kc*32+quad*8+j] ----
        v8s a[4];
#pragma unroll
        for (int kc = 0; kc < 4; ++kc) {
            union { v8s s8; unsigned u[4]; } av;
            av.u[0] = pk_bf2(pf[2 * kc].x,     pf[2 * kc].y);
            av.u[1] = pk_bf2(pf[2 * kc].z,     pf[2 * kc].w);
            av.u[2] = pk_bf2(pf[2 * kc + 1].x, pf[2 * kc + 1].y);
            av.u[3] = pk_bf2(pf[2 * kc + 1].z, pf[2 * kc + 1].w);
            a[kc] = av.s8;
        }

        // ---- prefetch next strip's A tile (overlaps MFMA + epilogue) ----
        if (s < 7) {
            const int n1 = strip + 16 + m;
            const bool va = (n1 < N);
            const float* arow = feat_i + (size_t)(va ? n1 : 0) * DIM + quad * 8;
#pragma unroll
            for (int kc = 0; kc < 4; ++kc) {
                pf[2 * kc]     = va ? *(const float4*)(arow + kc * 32)     : make_float4(0.f, 0.f, 0.f, 0.f);
                pf[2 * kc + 1] = va ? *(const float4*)(arow + kc * 32 + 4) : make_float4(0.f, 0.f, 0.f, 0.f);
            }
        }

        // ---- MFMA: 8 col-tiles x 4 K-chunks ----
        v4f acc[8];
#pragma unroll
        for (int c = 0; c < 8; ++c) acc[c] = (v4f){0.f, 0.f, 0.f, 0.f};
#pragma unroll
        for (int c = 0; c < 8; ++c) {
            const unsigned short* brow = Blds + (c * 16 + m) * BSTRIDE + quad * 8;
#pragma unroll
            for (int kc = 0; kc < 4; ++kc) {
                v8s b = *(const v8s*)(brow + kc * 32);
                acc[c] = __builtin_amdgcn_mfma_f32_16x16x32_bf16(a[kc], b, acc[c], 0, 0, 0);
            }
        }

        // ---- epilogue: C row = quad*4 + r, col = c*16 + m ----
        float exq[4];
#pragma unroll
        for (int r = 0; r < 4; ++r) {
            const int node = strip + quad * 4 + r;
            const bool nv = (node < N);
            const int sg = nv ? seg[node] : 0;
            const float* qrow = qry + sg * DIM;
            float partial = 0.f;
#pragma unroll
            for (int c = 0; c < 8; ++c) {
                const int d = c * 16 + m;
                const float x = acc[c][r] + qrow[d];
                const float sig = __builtin_amdgcn_rcpf(1.0f + __expf(-x));
                partial += sig * We[d];
            }
            partial += __shfl_xor(partial, 1);
            partial += __shfl_xor(partial, 2);
            partial += __shfl_xor(partial, 4);
            partial += __shfl_xor(partial, 8);
            const float ex = __expf(partial);
            exq[r] = ex;
            if (m == 0 && nv) {
                const int slot = sg - sg_first;
                if (slot >= 0 && slot < NSLOT) atomicAdd(&dlds[slot], ex);
                else                           atomicAdd(denom + sg, ex);
            }
        }

        // ---- broadcast w = ex[strip+m] to the A-fragment owners of column m ----
        float w = 0.f;
#pragma unroll
        for (int r = 0; r < 4; ++r) {
            const float tv = __shfl(exq[r], (m >> 2) << 4);
            if ((m & 3) == r) w = tv;
        }
        const int n_a = strip + m;
        if (n_a >= N) w = 0.f;

        // ---- segment-boundary flush (to LDS), then accumulate w * feat_i (bf16-rounded) ----
        const int sg_col = seg[min(n_a, N - 1)];
        if (sg_col != cur_sg) {
            const int slot = cur_sg - sg_first;
            if (slot >= 0 && slot < NSLOT) {
                float* dst = slds + slot * DIM + quad * 8;
#pragma unroll
                for (int kc = 0; kc < 4; ++kc)
#pragma unroll
                    for (int j = 0; j < 8; ++j) {
                        atomicAdd(dst + kc * 32 + j, facc[kc * 8 + j]);
                        facc[kc * 8 + j] = 0.f;
                    }
            } else {
                float* dst = Wacc + (size_t)cur_sg * DIM + quad * 8;
#pragma unroll
                for (int kc = 0; kc < 4; ++kc)
#pragma unroll
                    for (int j = 0; j < 8; ++j) {
                        atomicAdd(dst + kc * 32 + j, facc[kc * 8 + j]);
                        facc[kc * 8 + j] = 0.f;
                    }
            }
            cur_sg = sg_col;
        }
#pragma unroll
        for (int kc = 0; kc < 4; ++kc)
#pragma unroll
            for (int j = 0; j < 8; ++j)
                facc[kc * 8 + j] += w * bf2f(a[kc][j]);
    }

    // final per-lane flush into LDS slots
    {
        const int slot = cur_sg - sg_first;
        if (slot >= 0 && slot < NSLOT) {
            float* dst = slds + slot * DIM + quad * 8;
#pragma unroll
            for (int kc = 0; kc < 4; ++kc)
#pragma unroll
                for (int j = 0; j < 8; ++j)
                    atomicAdd(dst + kc * 32 + j, facc[kc * 8 + j]);
        } else {
            float* dst = Wacc + (size_t)cur_sg * DIM + quad * 8;
#pragma unroll
            for (int kc = 0; kc < 4; ++kc)
#pragma unroll
                for (int j = 0; j < 8; ++j)
                    atomicAdd(dst + kc * 32 + j, facc[kc * 8 + j]);
        }
    }

    // ---- single block-level flush: distinct addresses per instruction ----
    __syncthreads();
    const int sg_last = seg[min(base_block + 511, N - 1)];
    const int nused = min(sg_last - sg_first + 1, NSLOT);
    for (int i = t; i < nused * DIM; i += 256) {
        const int sl = i >> 7, d = i & 127;
        const float v = slds[sl * DIM + d];
        if (v != 0.f) atomicAdd(Wacc + (size_t)(sg_first + sl) * DIM + d, v);
    }
    if (t < nused) {
        const float v = dlds[t];
        if (v != 0.f) atomicAdd(denom + sg_first + t, v);
    }
}

// ---------------- finalize: out[b][d] = Wacc[b][d] / denom[b] ----------------
__global__ void finalize_kernel(const float* __restrict__ Wacc,
                                const float* __restrict__ denom,
                                float* __restrict__ out) {
    const int b = blockIdx.x, t = threadIdx.x;
    const float d = denom[b];
    const float inv = (d > 0.f) ? 1.0f / d : 0.f;
    out[b * DIM + t] = Wacc[b * DIM + t] * inv;
}

extern "C" void kernel_launch(void* const* d_in, const int* in_sizes, int n_in,
                              void* d_out, int out_size, void* d_ws, size_t ws_size,
                              hipStream_t stream) {
    const float* feat_i = (const float*)d_in[0];
    const float* feat_u = (const float*)d_in[1];
    const int*   seg    = (const int*)d_in[2];
    const float* W_key  = (const float*)d_in[3];
    const float* W_user = (const float*)d_in[4];
    const float* b_user = (const float*)d_in[5];
    const float* W_e    = (const float*)d_in[6];
    float* out = (float*)d_out;

    const int N = in_sizes[2];
    const int B = in_sizes[1] / DIM;

    // workspace layout
    char* ws = (char*)d_ws;
    float*          qry   = (float*)ws;                          // 131072 B
    unsigned short* WkT   = (unsigned short*)(ws + 131072);      // 34816 B
    float*          denom = (float*)(ws + 131072 + 34816);       // B*4 (pad to 4096)
    float*          Wacc  = (float*)(ws + 131072 + 34816 + 4096);// B*DIM*4 = 131072 B

    hipMemsetAsync(denom, 0, (size_t)B * sizeof(float), stream);
    hipMemsetAsync(Wacc, 0, (size_t)B * DIM * sizeof(float), stream);

    qry_kernel<<<B, DIM, 0, stream>>>(feat_u, W_user, b_user, qry);
    wkt_kernel<<<(DIM * DIM) / 256, 256, 0, stream>>>(W_key, WkT);

    const int nblk = (N + 511) / 512;
    e_fused_kernel<<<nblk, 256, 0, stream>>>(feat_i, seg, WkT, qry, W_e, Wacc, denom, N);

    finalize_kernel<<<B, DIM, 0, stream>>>(Wacc, denom, out);
}